// Round 2
// baseline (3049.456 us; speedup 1.0000x reference)
//
#include <hip/hip_runtime.h>
#include <hip/hip_bf16.h>
#include <cmath>
#include <cstddef>

// Shapes (fixed): U=2048, B=4, D=512, NHEAD=8, dh=64, R=S=M=64
// Q = 2176, KV = 2176, rows = Q*B = 8704
#define QLEN 2176
#define KVLEN 2176
#define NROWS 8704
#define DMODEL 512
#define NEG_INF_V -100000000.0f
#define NMASK ((size_t)QLEN * (size_t)KVLEN)

// ---------------- attention_mask dtype detection + canonicalization ----------------
// The reference's attention_mask is a jax bool array; the harness may hand it to us
// as uint8 (1B), int32 (4B, values 0/1), or float32 (4B, values 0/1.0f). Detect by
// byte signature: int32 {0,1} -> bytes at offsets 1,2,3 (mod 4) are ALL zero;
// float32 {0,1.0f} -> bytes at offsets 0,1 (mod 4) all zero, some at 2,3 nonzero;
// uint8 bool(p=0.3) -> ~30% nonzero at every offset (P(misclassify) ~ 0.7^4096 ~ 0).
__global__ void detect_mask_kernel(const unsigned char* __restrict__ m, int* __restrict__ flag) {
    if (blockIdx.x == 0 && threadIdx.x == 0) {
        unsigned int nz123 = 0, nz01 = 0, nz23 = 0;
        for (int g = 0; g < 4096; ++g) {
            unsigned char b0 = m[4 * g + 0], b1 = m[4 * g + 1];
            unsigned char b2 = m[4 * g + 2], b3 = m[4 * g + 3];
            if (b1 | b2 | b3) nz123++;
            if (b0 | b1) nz01++;
            if (b2 | b3) nz23++;
        }
        int f;
        if (nz123 == 0)           f = 0;  // int32 {0,1}
        else if (nz01 == 0 && nz23) f = 2; // float32 {0,1.0f}
        else                       f = 1;  // uint8 / bool
        *flag = f;
    }
}

__global__ __launch_bounds__(256) void canon_mask_kernel(
    const void* __restrict__ mraw, const int* __restrict__ flag,
    unsigned char* __restrict__ canon)
{
    size_t idx = (size_t)blockIdx.x * 256 + threadIdx.x;
    if (idx >= NMASK) return;
    int f = *flag;   // uniform
    unsigned char v;
    if (f == 0)      v = (((const int*)mraw)[idx] != 0);
    else if (f == 2) v = (((const float*)mraw)[idx] != 0.0f);
    else             v = (((const unsigned char*)mraw)[idx] != 0);
    canon[idx] = v;
}

// ---------------- GEMM: out(M x N) = concat(segs)(M x 512) @ W(512 x N) + bias ---------
#define GBM 128
#define GBN 128
#define GBK 16
#define APITCH 132

template<int MODE>
__global__ __launch_bounds__(256) void gemm_seg(
    const float* __restrict__ s0, const float* __restrict__ s1, const float* __restrict__ s2,
    int b0, int b1,
    const float* __restrict__ W, const float* __restrict__ bias,
    float* __restrict__ out, int N)
{
    __shared__ float As[GBK][APITCH];   // transposed A tile [k][m]
    __shared__ float Bs[GBK][GBN];      // B tile [k][n]
    const int tid = threadIdx.x;
    const int tx = tid & 15, ty = tid >> 4;
    const int bm = blockIdx.x, bn = blockIdx.y;

    float acc[8][8] = {};

    for (int k0 = 0; k0 < DMODEL; k0 += GBK) {
        // load A tile: 128 rows x 16 k-cols, gathered across 3 segments
        #pragma unroll
        for (int i = 0; i < 2; ++i) {
            int c = i * 256 + tid;        // 512 float4 chunks
            int row = c >> 2, col = (c & 3) * 4;
            int gr = bm * GBM + row;
            const float* src;
            if (gr < b0)      src = s0 + (size_t)gr * DMODEL;
            else if (gr < b1) src = s1 + (size_t)(gr - b0) * DMODEL;
            else              src = s2 + (size_t)(gr - b1) * DMODEL;
            float4 v = *(const float4*)(src + k0 + col);
            As[col + 0][row] = v.x; As[col + 1][row] = v.y;
            As[col + 2][row] = v.z; As[col + 3][row] = v.w;
        }
        // load B tile: 16 rows x 128 cols
        #pragma unroll
        for (int i = 0; i < 2; ++i) {
            int c = i * 256 + tid;
            int row = c >> 5, col = (c & 31) * 4;
            float4 v = *(const float4*)(W + (size_t)(k0 + row) * N + bn * GBN + col);
            *(float4*)&Bs[row][col] = v;
        }
        __syncthreads();
        #pragma unroll
        for (int k = 0; k < GBK; ++k) {
            float a[8], bb[8];
            *(float4*)&a[0] = *(float4*)&As[k][ty * 8];
            *(float4*)&a[4] = *(float4*)&As[k][ty * 8 + 4];
            *(float4*)&bb[0] = *(float4*)&Bs[k][tx * 8];
            *(float4*)&bb[4] = *(float4*)&Bs[k][tx * 8 + 4];
            #pragma unroll
            for (int i2 = 0; i2 < 8; ++i2)
                #pragma unroll
                for (int j2 = 0; j2 < 8; ++j2)
                    acc[i2][j2] += a[i2] * bb[j2];
        }
        __syncthreads();
    }

    // epilogue
    #pragma unroll
    for (int i2 = 0; i2 < 8; ++i2) {
        int gr = bm * GBM + ty * 8 + i2;
        int gc0 = bn * GBN + tx * 8;
        if (MODE == 0) {
            #pragma unroll
            for (int j2 = 0; j2 < 8; ++j2)
                out[(size_t)gr * N + gc0 + j2] = acc[i2][j2] + bias[gc0 + j2];
        } else {
            // routing epilogue: rows r = q*4 + b over outputs (2176,4,512)
            int q = gr >> 2, bb2 = gr & 3;
            if (q < 2112) {
                #pragma unroll
                for (int j2 = 0; j2 < 8; ++j2)
                    out[(size_t)gr * DMODEL + gc0 + j2] = acc[i2][j2] + bias[gc0 + j2];
            } else if (q < 2175) {
                size_t base = (size_t)2112 * 4 * DMODEL + ((size_t)(q - 2112) * 4 + bb2) * DMODEL;
                #pragma unroll
                for (int j2 = 0; j2 < 8; ++j2) {
                    float v = acc[i2][j2] + bias[gc0 + j2];
                    v = fminf(10.0f, fmaxf(-10.0f, v));
                    out[base + gc0 + j2] = v;
                }
            } // q == 2175 (last summary row) is dropped
        }
    }
}

// ---------------- Flash attention, f32, one block per (q-tile, b, h) --------------------
#define PITCH 68

__global__ __launch_bounds__(256) void attn_kernel(
    const float* __restrict__ query,    // (2176*4, 512), row = q*4+b
    const float* __restrict__ kvbuf,    // (2176*4, 1024): [:512]=K, [512:]=V
    const unsigned char* __restrict__ mask, // (2176, 2176) canonical u8
    const int* __restrict__ lengths,
    float* __restrict__ attnout)        // (2176*4, 512)
{
    __shared__ float Qs[64][PITCH];
    __shared__ float Ks[64][PITCH];
    __shared__ float Vst[64][PITCH];    // V transposed: [d][kv]
    __shared__ float Ps[64][PITCH];

    const int qt = blockIdx.x;          // 0..33
    const int bh = blockIdx.y;          // 0..31
    const int b = bh >> 3, h = bh & 7;
    const int tid = threadIdx.x;
    const int tx = tid & 15, ty = tid >> 4;
    const int kvlim = 128 + lengths[b]; // pad mask: kv >= kvlim -> NEG_INF
    const int q0 = qt * 64;

    // load Q tile (64 q-rows x 64 dh)
    #pragma unroll
    for (int i = 0; i < 4; ++i) {
        int c = i * 256 + tid;
        int row = c >> 4, col = (c & 15) * 4;
        float4 v = *(const float4*)(query + ((size_t)(q0 + row) * 4 + b) * DMODEL + h * 64 + col);
        *(float4*)&Qs[row][col] = v;
    }

    float O[4][4] = {};
    float m[4], l[4];
    #pragma unroll
    for (int i = 0; i < 4; ++i) { m[i] = -INFINITY; l[i] = 0.0f; }

    for (int kt = 0; kt < 34; ++kt) {
        int k0 = kt * 64;
        __syncthreads();  // previous iteration done with Ks/Vst (also fences Q load on kt=0)
        #pragma unroll
        for (int i = 0; i < 4; ++i) {
            int c = i * 256 + tid;
            int row = c >> 4, col = (c & 15) * 4;
            const float* base = kvbuf + ((size_t)(k0 + row) * 4 + b) * 1024 + h * 64;
            float4 kvv = *(const float4*)(base + col);
            *(float4*)&Ks[row][col] = kvv;
            float4 vv = *(const float4*)(base + 512 + col);
            Vst[col + 0][row] = vv.x; Vst[col + 1][row] = vv.y;
            Vst[col + 2][row] = vv.z; Vst[col + 3][row] = vv.w;
        }
        __syncthreads();

        // S = Q K^T  (thread owns rows ty+16*ii, cols tx+16*jj)
        float s[4][4] = {};
        #pragma unroll
        for (int d4 = 0; d4 < 16; ++d4) {
            float4 qv[4], kv4[4];
            #pragma unroll
            for (int ii = 0; ii < 4; ++ii) qv[ii] = *(float4*)&Qs[ty + 16 * ii][d4 * 4];
            #pragma unroll
            for (int jj = 0; jj < 4; ++jj) kv4[jj] = *(float4*)&Ks[tx + 16 * jj][d4 * 4];
            #pragma unroll
            for (int ii = 0; ii < 4; ++ii)
                #pragma unroll
                for (int jj = 0; jj < 4; ++jj)
                    s[ii][jj] += qv[ii].x * kv4[jj].x + qv[ii].y * kv4[jj].y
                               + qv[ii].z * kv4[jj].z + qv[ii].w * kv4[jj].w;
        }

        // masks + online softmax
        #pragma unroll
        for (int ii = 0; ii < 4; ++ii) {
            int qg = q0 + ty + 16 * ii;
            float rmax = -INFINITY;
            float pv[4];
            #pragma unroll
            for (int jj = 0; jj < 4; ++jj) {
                int kg = k0 + tx + 16 * jj;
                float lg = s[ii][jj] * 0.125f;   // scaling = dh^-0.5
                if (mask[(size_t)qg * KVLEN + kg] || kg >= kvlim) lg = NEG_INF_V;
                pv[jj] = lg;
                rmax = fmaxf(rmax, lg);
            }
            #pragma unroll
            for (int off = 8; off; off >>= 1) rmax = fmaxf(rmax, __shfl_xor(rmax, off));
            float mn = fmaxf(m[ii], rmax);
            float f = __expf(m[ii] - mn);
            float rs = 0.0f;
            #pragma unroll
            for (int jj = 0; jj < 4; ++jj) { pv[jj] = __expf(pv[jj] - mn); rs += pv[jj]; }
            #pragma unroll
            for (int off = 8; off; off >>= 1) rs += __shfl_xor(rs, off);
            l[ii] = l[ii] * f + rs;
            m[ii] = mn;
            #pragma unroll
            for (int jj = 0; jj < 4; ++jj) {
                O[ii][jj] *= f;
                Ps[ty + 16 * ii][tx + 16 * jj] = pv[jj];
            }
        }
        __syncthreads();

        // O += P @ V   (O cols d = tx+16*jj)
        #pragma unroll
        for (int k4 = 0; k4 < 16; ++k4) {
            float4 pr[4], vr[4];
            #pragma unroll
            for (int ii = 0; ii < 4; ++ii) pr[ii] = *(float4*)&Ps[ty + 16 * ii][k4 * 4];
            #pragma unroll
            for (int jj = 0; jj < 4; ++jj) vr[jj] = *(float4*)&Vst[tx + 16 * jj][k4 * 4];
            #pragma unroll
            for (int ii = 0; ii < 4; ++ii)
                #pragma unroll
                for (int jj = 0; jj < 4; ++jj)
                    O[ii][jj] += pr[ii].x * vr[jj].x + pr[ii].y * vr[jj].y
                               + pr[ii].z * vr[jj].z + pr[ii].w * vr[jj].w;
        }
    }

    // normalize and write
    #pragma unroll
    for (int ii = 0; ii < 4; ++ii) {
        int qg = q0 + ty + 16 * ii;
        float inv = 1.0f / l[ii];
        #pragma unroll
        for (int jj = 0; jj < 4; ++jj) {
            int d = tx + 16 * jj;
            attnout[((size_t)qg * 4 + b) * DMODEL + h * 64 + d] = O[ii][jj] * inv;
        }
    }
}

extern "C" void kernel_launch(void* const* d_in, const int* in_sizes, int n_in,
                              void* d_out, int out_size, void* d_ws, size_t ws_size,
                              hipStream_t stream) {
    const float* utterance     = (const float*)d_in[0];
    const int*   lengths       = (const int*)d_in[1];
    const float* right_context = (const float*)d_in[2];
    const float* summary       = (const float*)d_in[3];
    const float* memory        = (const float*)d_in[4];
    const void*  mask_raw      = d_in[5];
    const float* w_q   = (const float*)d_in[6];
    const float* b_q   = (const float*)d_in[7];
    const float* w_kv  = (const float*)d_in[8];
    const float* b_kv  = (const float*)d_in[9];
    const float* w_out = (const float*)d_in[10];
    const float* b_out = (const float*)d_in[11];
    float* out = (float*)d_out;

    float* query = (float*)d_ws;                          // 8704 x 512 f32
    float* kvbuf = query + (size_t)NROWS * DMODEL;        // 8704 x 1024 f32
    float* attnb = kvbuf + (size_t)NROWS * 1024;          // 8704 x 512 f32
    unsigned char* canon = (unsigned char*)(attnb + (size_t)NROWS * DMODEL); // 2176x2176 u8
    int* maskflag = (int*)(canon + ((NMASK + 15) & ~(size_t)15));

    // mask dtype detect + canonicalize (stream-ordered: flag ready before canon)
    detect_mask_kernel<<<1, 64, 0, stream>>>((const unsigned char*)mask_raw, maskflag);
    canon_mask_kernel<<<(int)((NMASK + 255) / 256), 256, 0, stream>>>(mask_raw, maskflag, canon);

    // q_in = [right_context(256 rows), utterance(8192), summary(256)]
    gemm_seg<0><<<dim3(68, 4), 256, 0, stream>>>(
        right_context, utterance, summary, 256, 8448, w_q, b_q, query, 512);
    // kv_in = [memory(256), right_context(256), utterance(8192)]
    gemm_seg<0><<<dim3(68, 8), 256, 0, stream>>>(
        memory, right_context, utterance, 256, 512, w_kv, b_kv, kvbuf, 1024);
    // attention
    attn_kernel<<<dim3(34, 32), 256, 0, stream>>>(query, kvbuf, canon, lengths, attnb);
    // output projection + split/clip routing
    gemm_seg<1><<<dim3(68, 4), 256, 0, stream>>>(
        attnb, attnb, attnb, 0, 0, w_out, b_out, out, 512);
}

// Round 3
// 549.121 us; speedup vs baseline: 5.5533x; 5.5533x over previous
//
#include <hip/hip_runtime.h>
#include <cmath>
#include <cstddef>

// Shapes (fixed): U=2048, B=4, D=512, NHEAD=8, dh=64, R=S=M=64
// Q = KV = 2176, rows = 8704
#define QLEN 2176
#define NROWS 8704
#define NEG_INF_V -100000000.0f
#define NMASK ((size_t)QLEN * (size_t)QLEN)

typedef __attribute__((ext_vector_type(8))) short short8;
typedef __attribute__((ext_vector_type(4))) float f32x4;
typedef unsigned short ushort_t;

#define MFMA16(A, B, C) __builtin_amdgcn_mfma_f32_16x16x32_bf16(A, B, C, 0, 0, 0)

__device__ __forceinline__ ushort_t f2bf(float f) {
    unsigned int u = __builtin_bit_cast(unsigned int, f);
    u += 0x7FFFu + ((u >> 16) & 1u);   // RNE
    return (ushort_t)(u >> 16);
}

// ---------------- mask dtype detect + canonicalize (verified in round 1) ----------------
__global__ void detect_mask_kernel(const unsigned char* __restrict__ m, int* __restrict__ flag) {
    if (blockIdx.x == 0 && threadIdx.x == 0) {
        unsigned int nz123 = 0, nz01 = 0, nz23 = 0;
        for (int g = 0; g < 4096; ++g) {
            unsigned char b0 = m[4 * g + 0], b1 = m[4 * g + 1];
            unsigned char b2 = m[4 * g + 2], b3 = m[4 * g + 3];
            if (b1 | b2 | b3) nz123++;
            if (b0 | b1) nz01++;
            if (b2 | b3) nz23++;
        }
        int f;
        if (nz123 == 0)             f = 0;  // int32 {0,1}
        else if (nz01 == 0 && nz23) f = 2;  // float32 {0,1.0f}
        else                        f = 1;  // uint8 bool
        *flag = f;
    }
}

__global__ __launch_bounds__(256) void canon_mask_kernel(
    const void* __restrict__ mraw, const int* __restrict__ flag,
    unsigned char* __restrict__ canon)
{
    size_t idx = (size_t)blockIdx.x * 256 + threadIdx.x;
    if (idx >= NMASK) return;
    int f = *flag;
    unsigned char v;
    if (f == 0)      v = (((const int*)mraw)[idx] != 0);
    else if (f == 2) v = (((const float*)mraw)[idx] != 0.0f);
    else             v = (((const unsigned char*)mraw)[idx] != 0);
    canon[idx] = v;
}

// ---------------- concat 3 segments (f32) -> bf16 [8704][512] ----------------
__global__ __launch_bounds__(256) void conv_concat(
    const float* __restrict__ s0, const float* __restrict__ s1, const float* __restrict__ s2,
    int b0, int b1, ushort_t* __restrict__ dst)
{
    int c = blockIdx.x * 256 + threadIdx.x;     // chunk of 8 elems
    int row = c >> 6, ch = c & 63;
    if (row >= NROWS) return;
    const float* src;
    if (row < b0)      src = s0 + (size_t)row * 512;
    else if (row < b1) src = s1 + (size_t)(row - b0) * 512;
    else               src = s2 + (size_t)(row - b1) * 512;
    float4 v0 = *(const float4*)(src + ch * 8);
    float4 v1 = *(const float4*)(src + ch * 8 + 4);
    short8 o;
    o[0] = (short)f2bf(v0.x); o[1] = (short)f2bf(v0.y);
    o[2] = (short)f2bf(v0.z); o[3] = (short)f2bf(v0.w);
    o[4] = (short)f2bf(v1.x); o[5] = (short)f2bf(v1.y);
    o[6] = (short)f2bf(v1.z); o[7] = (short)f2bf(v1.w);
    *(short8*)(dst + (size_t)row * 512 + ch * 8) = o;
}

// ---------------- W [512][N] f32 -> Wt [N][512] bf16 ----------------
__global__ __launch_bounds__(256) void transpose_w(
    const float* __restrict__ W, ushort_t* __restrict__ Wt, int N)
{
    __shared__ float t[32][33];
    int n0 = blockIdx.x * 32, k0 = blockIdx.y * 32;
    int tx = threadIdx.x, ty = threadIdx.y;  // block (32,8)
    #pragma unroll
    for (int i = 0; i < 4; ++i)
        t[ty + 8 * i][tx] = W[(size_t)(k0 + ty + 8 * i) * N + n0 + tx];
    __syncthreads();
    #pragma unroll
    for (int i = 0; i < 4; ++i)
        Wt[(size_t)(n0 + ty + 8 * i) * 512 + k0 + tx] = f2bf(t[tx][ty + 8 * i]);
}

// ---------------- bf16 MFMA GEMM: C[M][N] = A[M][512] @ Bt[N][512]^T + bias ----------------
// MODE 0: scatter bf16 to [bh][2176][64] (dst0 = cols<512, dst1 = cols>=512), scaled
// MODE 1: f32 routing epilogue to final output
template<int MODE>
__global__ __launch_bounds__(256) void gemm_mfma(
    const ushort_t* __restrict__ A, const ushort_t* __restrict__ Bt,
    const float* __restrict__ bias, float scale,
    ushort_t* __restrict__ dst0, ushort_t* __restrict__ dst1,
    float* __restrict__ dstf)
{
    __shared__ __align__(16) ushort_t As[128][40];   // [m][k], pad->stride 80B (2-way free)
    __shared__ __align__(16) ushort_t Bs[128][40];   // [n][k]
    const int tid = threadIdx.x;
    const int wid = tid >> 6, lane = tid & 63, lr = lane & 15, lg = lane >> 4;
    const int wm = wid >> 1, wn = wid & 1;
    const int bm = blockIdx.x, bn = blockIdx.y;

    f32x4 acc[4][4] = {};

    for (int k0 = 0; k0 < 512; k0 += 32) {
        __syncthreads();
        #pragma unroll
        for (int p = 0; p < 2; ++p) {
            int c = p * 256 + tid;
            int row = c >> 2, ch = c & 3;
            *(short8*)&As[row][ch * 8] =
                *(const short8*)(A + (size_t)(bm * 128 + row) * 512 + k0 + ch * 8);
            *(short8*)&Bs[row][ch * 8] =
                *(const short8*)(Bt + (size_t)(bn * 128 + row) * 512 + k0 + ch * 8);
        }
        __syncthreads();
        short8 af[4], bf[4];
        #pragma unroll
        for (int i = 0; i < 4; ++i) {
            af[i] = *(const short8*)&As[wm * 64 + i * 16 + lr][lg * 8];
            bf[i] = *(const short8*)&Bs[wn * 64 + i * 16 + lr][lg * 8];
        }
        #pragma unroll
        for (int i = 0; i < 4; ++i)
            #pragma unroll
            for (int j = 0; j < 4; ++j)
                acc[i][j] = MFMA16(af[i], bf[j], acc[i][j]);
    }

    #pragma unroll
    for (int i = 0; i < 4; ++i) {
        #pragma unroll
        for (int j = 0; j < 4; ++j) {
            int gc = bn * 128 + wn * 64 + j * 16 + lr;
            float bv = bias[gc];
            #pragma unroll
            for (int r = 0; r < 4; ++r) {
                int gr = bm * 128 + wm * 64 + i * 16 + lg * 4 + r;
                float v = (acc[i][j][r] + bv) * scale;
                if (MODE == 0) {
                    int cc = gc;
                    ushort_t* d = dst0;
                    if (cc >= 512) { cc -= 512; d = dst1; }
                    int pos = gr >> 2, bb = gr & 3;
                    d[(((size_t)bb * 8 + (cc >> 6)) * QLEN + pos) * 64 + (cc & 63)] = f2bf(v);
                } else {
                    int q = gr >> 2, bb = gr & 3;
                    if (q < 2112) {
                        dstf[(size_t)gr * 512 + gc] = v;
                    } else if (q < 2175) {
                        float cv = fminf(10.0f, fmaxf(-10.0f, v));
                        dstf[(size_t)2112 * 4 * 512 + ((size_t)(q - 2112) * 4 + bb) * 512 + gc] = cv;
                    } // q == 2175 dropped
                }
            }
        }
    }
}

// ---------------- Flash attention, bf16 MFMA ----------------
// grid (34 q-tiles, 32 bh). 4 waves x 16 q-rows. KV tile 64.
// Qa/Ka/Va layout: [bh][2176][64] bf16, Q pre-scaled by dh^-0.5.
__global__ __launch_bounds__(256) void attn_mfma(
    const ushort_t* __restrict__ Qa, const ushort_t* __restrict__ Ka,
    const ushort_t* __restrict__ Va,
    const unsigned char* __restrict__ mask, const int* __restrict__ lengths,
    ushort_t* __restrict__ attnb)   // [q*4+b][512] bf16
{
    __shared__ __align__(16) ushort_t Ks[64][72];      // [kv][dh], stride 144B
    __shared__ __align__(16) ushort_t Vt[64][72];      // [dh][kv]
    __shared__ __align__(16) ushort_t Pl[4][16][72];   // per-wave [q][kv]

    const int qt = blockIdx.x, bh = blockIdx.y;
    const int b = bh >> 3, h = bh & 7;
    const int tid = threadIdx.x;
    const int wq = tid >> 6, lane = tid & 63, lr = lane & 15, lg = lane >> 4;
    const int kvlim = 128 + lengths[b];
    const size_t hb = (size_t)bh * QLEN * 64;
    const int q0 = qt * 64 + wq * 16;

    // Q fragments (A operand): rows lr, k = kg*32 + lg*8 + j
    short8 aq[2];
    #pragma unroll
    for (int kg = 0; kg < 2; ++kg)
        aq[kg] = *(const short8*)(Qa + hb + (size_t)(q0 + lr) * 64 + kg * 32 + lg * 8);

    f32x4 oacc[4] = {};
    float mrow[4], lrow[4];
    #pragma unroll
    for (int r = 0; r < 4; ++r) { mrow[r] = -INFINITY; lrow[r] = 0.0f; }

    for (int kt = 0; kt < 34; ++kt) {
        const int k0 = kt * 64;
        __syncthreads();   // previous tile's reads of Ks/Vt done
        // stage K [kv][dh]
        #pragma unroll
        for (int p = 0; p < 2; ++p) {
            int c = p * 256 + tid;
            int row = c >> 3, ch = c & 7;
            *(short8*)&Ks[row][ch * 8] =
                *(const short8*)(Ka + hb + (size_t)(k0 + row) * 64 + ch * 8);
        }
        // stage V transposed [dh][kv] (lanes span kv -> conflict-free scalar writes)
        #pragma unroll
        for (int p = 0; p < 2; ++p) {
            int c = p * 256 + tid;
            int kv = c & 63, ch = (p * 256 + tid) >> 6;
            short8 v = *(const short8*)(Va + hb + (size_t)(k0 + kv) * 64 + ch * 8);
            #pragma unroll
            for (int i = 0; i < 8; ++i) Vt[ch * 8 + i][kv] = (ushort_t)v[i];
        }
        __syncthreads();

        // S = Q K^T : 8 MFMA -> S[16][64], C rows lg*4+r, cols f*16+lr
        f32x4 sacc[4] = {};
        #pragma unroll
        for (int kg = 0; kg < 2; ++kg)
            #pragma unroll
            for (int f = 0; f < 4; ++f) {
                short8 bk = *(const short8*)&Ks[f * 16 + lr][kg * 32 + lg * 8];
                sacc[f] = MFMA16(aq[kg], bk, sacc[f]);
            }

        // mask + online softmax per q-row (16-lane groups)
        #pragma unroll
        for (int r = 0; r < 4; ++r) {
            int qg = q0 + lg * 4 + r;
            const unsigned char* mrowp = mask + (size_t)qg * QLEN + k0;
            float sv[4];
            float rmax = -INFINITY;
            #pragma unroll
            for (int f = 0; f < 4; ++f) {
                int kc = f * 16 + lr;
                float x = sacc[f][r];
                if (mrowp[kc] || (k0 + kc) >= kvlim) x = NEG_INF_V;
                sv[f] = x;
                rmax = fmaxf(rmax, x);
            }
            #pragma unroll
            for (int off = 8; off; off >>= 1) rmax = fmaxf(rmax, __shfl_xor(rmax, off));
            float mn = fmaxf(mrow[r], rmax);
            float fac = __expf(mrow[r] - mn);
            float rs = 0.0f;
            #pragma unroll
            for (int f = 0; f < 4; ++f) { sv[f] = __expf(sv[f] - mn); rs += sv[f]; }
            #pragma unroll
            for (int off = 8; off; off >>= 1) rs += __shfl_xor(rs, off);
            lrow[r] = lrow[r] * fac + rs;
            mrow[r] = mn;
            #pragma unroll
            for (int n = 0; n < 4; ++n) oacc[n][r] *= fac;
            #pragma unroll
            for (int f = 0; f < 4; ++f)
                Pl[wq][lg * 4 + r][f * 16 + lr] = f2bf(sv[f]);
        }

        // O += P V : A = P rows lr, B = V via Vt
        #pragma unroll
        for (int kg = 0; kg < 2; ++kg) {
            short8 pa = *(const short8*)&Pl[wq][lr][kg * 32 + lg * 8];
            #pragma unroll
            for (int n = 0; n < 4; ++n) {
                short8 bv = *(const short8*)&Vt[n * 16 + lr][kg * 32 + lg * 8];
                oacc[n] = MFMA16(pa, bv, oacc[n]);
            }
        }
    }

    // normalize + write bf16 [q*4+b][h*64+d]
    #pragma unroll
    for (int r = 0; r < 4; ++r) {
        int qg = q0 + lg * 4 + r;
        float inv = 1.0f / lrow[r];
        #pragma unroll
        for (int n = 0; n < 4; ++n)
            attnb[((size_t)qg * 4 + b) * 512 + h * 64 + n * 16 + lr] =
                f2bf(oacc[n][r] * inv);
    }
}

extern "C" void kernel_launch(void* const* d_in, const int* in_sizes, int n_in,
                              void* d_out, int out_size, void* d_ws, size_t ws_size,
                              hipStream_t stream) {
    const float* utterance     = (const float*)d_in[0];
    const int*   lengths       = (const int*)d_in[1];
    const float* right_context = (const float*)d_in[2];
    const float* summary       = (const float*)d_in[3];
    const float* memory        = (const float*)d_in[4];
    const void*  mask_raw      = d_in[5];
    const float* w_q   = (const float*)d_in[6];
    const float* b_q   = (const float*)d_in[7];
    const float* w_kv  = (const float*)d_in[8];
    const float* b_kv  = (const float*)d_in[9];
    const float* w_out = (const float*)d_in[10];
    const float* b_out = (const float*)d_in[11];
    float* out = (float*)d_out;

    char* ws = (char*)d_ws;
    const size_t SZ = (size_t)NROWS * 512 * 2;             // 8.9 MB per bf16 matrix
    ushort_t* qin    = (ushort_t*)(ws);                    // [8704][512]
    ushort_t* kvin   = (ushort_t*)(ws + SZ);
    ushort_t* q_attn = (ushort_t*)(ws + 2 * SZ);           // [bh][2176][64]
    ushort_t* k_attn = (ushort_t*)(ws + 3 * SZ);
    ushort_t* v_attn = (ushort_t*)(ws + 4 * SZ);
    ushort_t* attnb  = (ushort_t*)(ws + 5 * SZ);
    ushort_t* wtq    = (ushort_t*)(ws + 6 * SZ);           // [512][512]
    ushort_t* wtkv   = wtq + (size_t)512 * 512;            // [1024][512]
    ushort_t* wtout  = wtkv + (size_t)1024 * 512;          // [512][512]
    unsigned char* canon = (unsigned char*)(wtout + (size_t)512 * 512);
    int* maskflag = (int*)(canon + ((NMASK + 255) & ~(size_t)255));

    // mask canonicalization
    detect_mask_kernel<<<1, 64, 0, stream>>>((const unsigned char*)mask_raw, maskflag);
    canon_mask_kernel<<<(int)((NMASK + 255) / 256), 256, 0, stream>>>(mask_raw, maskflag, canon);

    // activations -> bf16 (concat layouts match reference)
    conv_concat<<<2176, 256, 0, stream>>>(right_context, utterance, summary, 256, 8448, qin);
    conv_concat<<<2176, 256, 0, stream>>>(memory, right_context, utterance, 256, 512, kvin);

    // weights -> transposed bf16 [N][K]
    transpose_w<<<dim3(16, 16), dim3(32, 8), 0, stream>>>(w_q, wtq, 512);
    transpose_w<<<dim3(32, 16), dim3(32, 8), 0, stream>>>(w_kv, wtkv, 1024);
    transpose_w<<<dim3(16, 16), dim3(32, 8), 0, stream>>>(w_out, wtout, 512);

    // projections (Q pre-scaled by dh^-0.5 = 0.125)
    gemm_mfma<0><<<dim3(68, 4), 256, 0, stream>>>(qin, wtq, b_q, 0.125f, q_attn, q_attn, nullptr);
    gemm_mfma<0><<<dim3(68, 8), 256, 0, stream>>>(kvin, wtkv, b_kv, 1.0f, k_attn, v_attn, nullptr);

    // attention
    attn_mfma<<<dim3(34, 32), 256, 0, stream>>>(q_attn, k_attn, v_attn, canon, lengths, attnb);

    // output projection + routing epilogue
    gemm_mfma<1><<<dim3(68, 4), 256, 0, stream>>>(attnb, wtout, b_out, 1.0f, nullptr, nullptr, out);
}

// Round 4
// 273.831 us; speedup vs baseline: 11.1363x; 2.0053x over previous
//
#include <hip/hip_runtime.h>
#include <cmath>
#include <cstddef>

// Shapes (fixed): U=2048, B=4, D=512, NHEAD=8, dh=64, R=S=M=64
// Q = KV = 2176, rows = 8704
#define QLEN 2176
#define NROWS 8704
#define NEG_INF_V -100000000.0f
#define NMASK ((size_t)QLEN * (size_t)QLEN)

typedef __attribute__((ext_vector_type(8))) short short8;
typedef __attribute__((ext_vector_type(4))) float f32x4;
typedef unsigned short ushort_t;

#define MFMA16(A, B, C) __builtin_amdgcn_mfma_f32_16x16x32_bf16(A, B, C, 0, 0, 0)

__device__ __forceinline__ ushort_t f2bf(float f) {
    unsigned int u = __builtin_bit_cast(unsigned int, f);
    u += 0x7FFFu + ((u >> 16) & 1u);   // RNE
    return (ushort_t)(u >> 16);
}

// ---------------- mask dtype detect (parallel) + canonicalize ----------------
// int32 {0,1}: bytes 1,2,3 (mod 4) all zero. float32 {0,1.0f}: bytes 0,1 all zero,
// some at 2,3 nonzero. uint8 bool(p=0.3): nonzero at every offset.
__global__ __launch_bounds__(256) void detect_mask_kernel(
    const unsigned int* __restrict__ m, int* __restrict__ flag)
{
    __shared__ unsigned int r123, r01, r23;
    if (threadIdx.x == 0) { r123 = 0; r01 = 0; r23 = 0; }
    __syncthreads();
    unsigned int a123 = 0, a01 = 0, a23 = 0;
    #pragma unroll
    for (int i = 0; i < 16; ++i) {
        unsigned int w = m[threadIdx.x * 16 + i];   // 4096 words = first 16KB
        a123 |= (w & 0xFFFFFF00u);
        a01  |= (w & 0x0000FFFFu);
        a23  |= (w & 0xFFFF0000u);
    }
    if (a123) atomicOr(&r123, 1u);
    if (a01)  atomicOr(&r01, 1u);
    if (a23)  atomicOr(&r23, 1u);
    __syncthreads();
    if (threadIdx.x == 0) {
        int f;
        if (!r123)            f = 0;  // int32 {0,1}
        else if (!r01 && r23) f = 2;  // float32 {0,1.0f}
        else                  f = 1;  // uint8 bool
        *flag = f;
    }
}

__global__ __launch_bounds__(256) void canon_mask_kernel(
    const void* __restrict__ mraw, const int* __restrict__ flag,
    unsigned char* __restrict__ canon)
{
    size_t idx = (size_t)blockIdx.x * 256 + threadIdx.x;
    if (idx >= NMASK) return;
    int f = *flag;
    unsigned char v;
    if (f == 0)      v = (((const int*)mraw)[idx] != 0);
    else if (f == 2) v = (((const float*)mraw)[idx] != 0.0f);
    else             v = (((const unsigned char*)mraw)[idx] != 0);
    canon[idx] = v;
}

// ---------------- concat 3 segments (f32) -> bf16 [8704][512] ----------------
__global__ __launch_bounds__(256) void conv_concat(
    const float* __restrict__ s0, const float* __restrict__ s1, const float* __restrict__ s2,
    int b0, int b1, ushort_t* __restrict__ dst)
{
    int c = blockIdx.x * 256 + threadIdx.x;     // chunk of 8 elems
    int row = c >> 6, ch = c & 63;
    if (row >= NROWS) return;
    const float* src;
    if (row < b0)      src = s0 + (size_t)row * 512;
    else if (row < b1) src = s1 + (size_t)(row - b0) * 512;
    else               src = s2 + (size_t)(row - b1) * 512;
    float4 v0 = *(const float4*)(src + ch * 8);
    float4 v1 = *(const float4*)(src + ch * 8 + 4);
    short8 o;
    o[0] = (short)f2bf(v0.x); o[1] = (short)f2bf(v0.y);
    o[2] = (short)f2bf(v0.z); o[3] = (short)f2bf(v0.w);
    o[4] = (short)f2bf(v1.x); o[5] = (short)f2bf(v1.y);
    o[6] = (short)f2bf(v1.z); o[7] = (short)f2bf(v1.w);
    *(short8*)(dst + (size_t)row * 512 + ch * 8) = o;
}

// ---------------- W [512][N] f32 -> Wt [N][512] bf16 ----------------
__global__ __launch_bounds__(256) void transpose_w(
    const float* __restrict__ W, ushort_t* __restrict__ Wt, int N)
{
    __shared__ float t[32][33];
    int n0 = blockIdx.x * 32, k0 = blockIdx.y * 32;
    int tx = threadIdx.x, ty = threadIdx.y;  // block (32,8)
    #pragma unroll
    for (int i = 0; i < 4; ++i)
        t[ty + 8 * i][tx] = W[(size_t)(k0 + ty + 8 * i) * N + n0 + tx];
    __syncthreads();
    #pragma unroll
    for (int i = 0; i < 4; ++i)
        Wt[(size_t)(n0 + ty + 8 * i) * 512 + k0 + tx] = f2bf(t[tx][ty + 8 * i]);
}

// ---------------- bf16 MFMA GEMM: C[M][N] = A[M][512] @ Bt[N][512]^T + bias ----------------
// MODE 0: scatter bf16 to [bh][2176][64] (dst0 = cols<512, dst1 = cols>=512), scaled
// MODE 1: f32 routing epilogue to final output
template<int MODE>
__global__ __launch_bounds__(256) void gemm_mfma(
    const ushort_t* __restrict__ A, const ushort_t* __restrict__ Bt,
    const float* __restrict__ bias, float scale,
    ushort_t* __restrict__ dst0, ushort_t* __restrict__ dst1,
    float* __restrict__ dstf)
{
    __shared__ __align__(16) ushort_t As[128][40];   // [m][k], pad->stride 80B (2-way free)
    __shared__ __align__(16) ushort_t Bs[128][40];   // [n][k]
    const int tid = threadIdx.x;
    const int wid = tid >> 6, lane = tid & 63, lr = lane & 15, lg = lane >> 4;
    const int wm = wid >> 1, wn = wid & 1;
    const int bm = blockIdx.x, bn = blockIdx.y;

    f32x4 acc[4][4] = {};

    for (int k0 = 0; k0 < 512; k0 += 32) {
        __syncthreads();
        #pragma unroll
        for (int p = 0; p < 2; ++p) {
            int c = p * 256 + tid;
            int row = c >> 2, ch = c & 3;
            *(short8*)&As[row][ch * 8] =
                *(const short8*)(A + (size_t)(bm * 128 + row) * 512 + k0 + ch * 8);
            *(short8*)&Bs[row][ch * 8] =
                *(const short8*)(Bt + (size_t)(bn * 128 + row) * 512 + k0 + ch * 8);
        }
        __syncthreads();
        short8 af[4], bf[4];
        #pragma unroll
        for (int i = 0; i < 4; ++i) {
            af[i] = *(const short8*)&As[wm * 64 + i * 16 + lr][lg * 8];
            bf[i] = *(const short8*)&Bs[wn * 64 + i * 16 + lr][lg * 8];
        }
        #pragma unroll
        for (int i = 0; i < 4; ++i)
            #pragma unroll
            for (int j = 0; j < 4; ++j)
                acc[i][j] = MFMA16(af[i], bf[j], acc[i][j]);
    }

    #pragma unroll
    for (int i = 0; i < 4; ++i) {
        #pragma unroll
        for (int j = 0; j < 4; ++j) {
            int gc = bn * 128 + wn * 64 + j * 16 + lr;
            float bv = bias[gc];
            #pragma unroll
            for (int r = 0; r < 4; ++r) {
                int gr = bm * 128 + wm * 64 + i * 16 + lg * 4 + r;
                float v = (acc[i][j][r] + bv) * scale;
                if (MODE == 0) {
                    int cc = gc;
                    ushort_t* d = dst0;
                    if (cc >= 512) { cc -= 512; d = dst1; }
                    int pos = gr >> 2, bb = gr & 3;
                    d[(((size_t)bb * 8 + (cc >> 6)) * QLEN + pos) * 64 + (cc & 63)] = f2bf(v);
                } else {
                    int q = gr >> 2, bb = gr & 3;
                    if (q < 2112) {
                        dstf[(size_t)gr * 512 + gc] = v;
                    } else if (q < 2175) {
                        float cv = fminf(10.0f, fmaxf(-10.0f, v));
                        dstf[(size_t)2112 * 4 * 512 + ((size_t)(q - 2112) * 4 + bb) * 512 + gc] = cv;
                    } // q == 2175 dropped
                }
            }
        }
    }
}

// ---------------- Flash attention, bf16 MFMA ----------------
// grid (34 q-tiles, 32 bh). 4 waves x 16 q-rows. KV tile 64.
// Qa/Ka/Va layout: [bh][2176][64] bf16, Q pre-scaled by dh^-0.5.
__global__ __launch_bounds__(256) void attn_mfma(
    const ushort_t* __restrict__ Qa, const ushort_t* __restrict__ Ka,
    const ushort_t* __restrict__ Va,
    const unsigned char* __restrict__ mask, const int* __restrict__ lengths,
    ushort_t* __restrict__ attnb)   // [q*4+b][512] bf16
{
    __shared__ __align__(16) ushort_t Ks[64][72];      // [kv][dh], stride 144B
    __shared__ __align__(16) ushort_t Vt[64][72];      // [dh][kv]
    __shared__ __align__(16) ushort_t Pl[4][16][72];   // per-wave [q][kv]

    const int qt = blockIdx.x, bh = blockIdx.y;
    const int b = bh >> 3, h = bh & 7;
    const int tid = threadIdx.x;
    const int wq = tid >> 6, lane = tid & 63, lr = lane & 15, lg = lane >> 4;
    const int kvlim = 128 + lengths[b];
    const size_t hb = (size_t)bh * QLEN * 64;
    const int q0 = qt * 64 + wq * 16;

    // Q fragments (A operand): rows lr, k = kg*32 + lg*8 + j
    short8 aq[2];
    #pragma unroll
    for (int kg = 0; kg < 2; ++kg)
        aq[kg] = *(const short8*)(Qa + hb + (size_t)(q0 + lr) * 64 + kg * 32 + lg * 8);

    f32x4 oacc[4] = {};
    float mrow[4], lrow[4];
    #pragma unroll
    for (int r = 0; r < 4; ++r) { mrow[r] = -INFINITY; lrow[r] = 0.0f; }

    for (int kt = 0; kt < 34; ++kt) {
        const int k0 = kt * 64;
        __syncthreads();   // previous tile's reads of Ks/Vt done
        // stage K [kv][dh]
        #pragma unroll
        for (int p = 0; p < 2; ++p) {
            int c = p * 256 + tid;
            int row = c >> 3, ch = c & 7;
            *(short8*)&Ks[row][ch * 8] =
                *(const short8*)(Ka + hb + (size_t)(k0 + row) * 64 + ch * 8);
        }
        // stage V transposed [dh][kv] (lanes span kv -> conflict-free scalar writes)
        #pragma unroll
        for (int p = 0; p < 2; ++p) {
            int c = p * 256 + tid;
            int kv = c & 63, ch = (p * 256 + tid) >> 6;
            short8 v = *(const short8*)(Va + hb + (size_t)(k0 + kv) * 64 + ch * 8);
            #pragma unroll
            for (int i = 0; i < 8; ++i) Vt[ch * 8 + i][kv] = (ushort_t)v[i];
        }
        __syncthreads();

        // S = Q K^T : 8 MFMA -> S[16][64], C rows lg*4+r, cols f*16+lr
        f32x4 sacc[4] = {};
        #pragma unroll
        for (int kg = 0; kg < 2; ++kg)
            #pragma unroll
            for (int f = 0; f < 4; ++f) {
                short8 bk = *(const short8*)&Ks[f * 16 + lr][kg * 32 + lg * 8];
                sacc[f] = MFMA16(aq[kg], bk, sacc[f]);
            }

        // mask + online softmax per q-row (16-lane groups)
        #pragma unroll
        for (int r = 0; r < 4; ++r) {
            int qg = q0 + lg * 4 + r;
            const unsigned char* mrowp = mask + (size_t)qg * QLEN + k0;
            float sv[4];
            float rmax = -INFINITY;
            #pragma unroll
            for (int f = 0; f < 4; ++f) {
                int kc = f * 16 + lr;
                float x = sacc[f][r];
                if (mrowp[kc] || (k0 + kc) >= kvlim) x = NEG_INF_V;
                sv[f] = x;
                rmax = fmaxf(rmax, x);
            }
            #pragma unroll
            for (int off = 8; off; off >>= 1) rmax = fmaxf(rmax, __shfl_xor(rmax, off));
            float mn = fmaxf(mrow[r], rmax);
            float fac = __expf(mrow[r] - mn);
            float rs = 0.0f;
            #pragma unroll
            for (int f = 0; f < 4; ++f) { sv[f] = __expf(sv[f] - mn); rs += sv[f]; }
            #pragma unroll
            for (int off = 8; off; off >>= 1) rs += __shfl_xor(rs, off);
            lrow[r] = lrow[r] * fac + rs;
            mrow[r] = mn;
            #pragma unroll
            for (int n = 0; n < 4; ++n) oacc[n][r] *= fac;
            #pragma unroll
            for (int f = 0; f < 4; ++f)
                Pl[wq][lg * 4 + r][f * 16 + lr] = f2bf(sv[f]);
        }

        // O += P V : A = P rows lr, B = V via Vt
        #pragma unroll
        for (int kg = 0; kg < 2; ++kg) {
            short8 pa = *(const short8*)&Pl[wq][lr][kg * 32 + lg * 8];
            #pragma unroll
            for (int n = 0; n < 4; ++n) {
                short8 bv = *(const short8*)&Vt[n * 16 + lr][kg * 32 + lg * 8];
                oacc[n] = MFMA16(pa, bv, oacc[n]);
            }
        }
    }

    // normalize + write bf16 [q*4+b][h*64+d]
    #pragma unroll
    for (int r = 0; r < 4; ++r) {
        int qg = q0 + lg * 4 + r;
        float inv = 1.0f / lrow[r];
        #pragma unroll
        for (int n = 0; n < 4; ++n)
            attnb[((size_t)qg * 4 + b) * 512 + h * 64 + n * 16 + lr] =
                f2bf(oacc[n][r] * inv);
    }
}

extern "C" void kernel_launch(void* const* d_in, const int* in_sizes, int n_in,
                              void* d_out, int out_size, void* d_ws, size_t ws_size,
                              hipStream_t stream) {
    const float* utterance     = (const float*)d_in[0];
    const int*   lengths       = (const int*)d_in[1];
    const float* right_context = (const float*)d_in[2];
    const float* summary       = (const float*)d_in[3];
    const float* memory        = (const float*)d_in[4];
    const void*  mask_raw      = d_in[5];
    const float* w_q   = (const float*)d_in[6];
    const float* b_q   = (const float*)d_in[7];
    const float* w_kv  = (const float*)d_in[8];
    const float* b_kv  = (const float*)d_in[9];
    const float* w_out = (const float*)d_in[10];
    const float* b_out = (const float*)d_in[11];
    float* out = (float*)d_out;

    char* ws = (char*)d_ws;
    const size_t SZ = (size_t)NROWS * 512 * 2;             // 8.9 MB per bf16 matrix
    ushort_t* qin    = (ushort_t*)(ws);                    // [8704][512]
    ushort_t* kvin   = (ushort_t*)(ws + SZ);
    ushort_t* q_attn = (ushort_t*)(ws + 2 * SZ);           // [bh][2176][64]
    ushort_t* k_attn = (ushort_t*)(ws + 3 * SZ);
    ushort_t* v_attn = (ushort_t*)(ws + 4 * SZ);
    ushort_t* attnb  = (ushort_t*)(ws + 5 * SZ);
    ushort_t* wtq    = (ushort_t*)(ws + 6 * SZ);           // [512][512]
    ushort_t* wtkv   = wtq + (size_t)512 * 512;            // [1024][512]
    ushort_t* wtout  = wtkv + (size_t)1024 * 512;          // [512][512]
    unsigned char* canon = (unsigned char*)(wtout + (size_t)512 * 512);
    int* maskflag = (int*)(canon + ((NMASK + 255) & ~(size_t)255));

    // mask canonicalization
    detect_mask_kernel<<<1, 256, 0, stream>>>((const unsigned int*)mask_raw, maskflag);
    canon_mask_kernel<<<(int)((NMASK + 255) / 256), 256, 0, stream>>>(mask_raw, maskflag, canon);

    // activations -> bf16 (concat layouts match reference)
    conv_concat<<<2176, 256, 0, stream>>>(right_context, utterance, summary, 256, 8448, qin);
    conv_concat<<<2176, 256, 0, stream>>>(memory, right_context, utterance, 256, 512, kvin);

    // weights -> transposed bf16 [N][K]
    transpose_w<<<dim3(16, 16), dim3(32, 8), 0, stream>>>(w_q, wtq, 512);
    transpose_w<<<dim3(32, 16), dim3(32, 8), 0, stream>>>(w_kv, wtkv, 1024);
    transpose_w<<<dim3(16, 16), dim3(32, 8), 0, stream>>>(w_out, wtout, 512);

    // projections (Q pre-scaled by dh^-0.5 = 0.125)
    gemm_mfma<0><<<dim3(68, 4), 256, 0, stream>>>(qin, wtq, b_q, 0.125f, q_attn, q_attn, nullptr);
    gemm_mfma<0><<<dim3(68, 8), 256, 0, stream>>>(kvin, wtkv, b_kv, 1.0f, k_attn, v_attn, nullptr);

    // attention
    attn_mfma<<<dim3(34, 32), 256, 0, stream>>>(q_attn, k_attn, v_attn, canon, lengths, attnb);

    // output projection + routing epilogue
    gemm_mfma<1><<<dim3(68, 4), 256, 0, stream>>>(attnb, wtout, b_out, 1.0f, nullptr, nullptr, out);
}

// Round 5
// 199.864 us; speedup vs baseline: 15.2576x; 1.3701x over previous
//
#include <hip/hip_runtime.h>
#include <cmath>
#include <cstddef>

// Shapes (fixed): U=2048, B=4, D=512, NHEAD=8, dh=64, R=S=M=64
// Q = KV = 2176, rows = 8704
#define QLEN 2176
#define NROWS 8704
#define NEG_INF_V -100000000.0f
#define NMASK ((size_t)QLEN * (size_t)QLEN)
#define NBITW (4 * QLEN * 68)   // per-b bitmask words

typedef __attribute__((ext_vector_type(8))) short short8;
typedef __attribute__((ext_vector_type(4))) float f32x4;
typedef __attribute__((ext_vector_type(16))) float f32x16;
typedef unsigned short ushort_t;

#define MFMA16(A, B, C) __builtin_amdgcn_mfma_f32_16x16x32_bf16(A, B, C, 0, 0, 0)
#define MFMA32(A, B, C) __builtin_amdgcn_mfma_f32_32x32x16_bf16(A, B, C, 0, 0, 0)

__device__ __forceinline__ ushort_t f2bf(float f) {
    unsigned int u = __builtin_bit_cast(unsigned int, f);
    u += 0x7FFFu + ((u >> 16) & 1u);   // RNE
    return (ushort_t)(u >> 16);
}

__device__ __forceinline__ unsigned int cvtpk_bf16(float lo, float hi) {
    unsigned int r;
    asm volatile("v_cvt_pk_bf16_f32 %0, %1, %2" : "=v"(r) : "v"(lo), "v"(hi));
    return r;
}

// ---------------- mask dtype detect (parallel, verified r3) ----------------
__global__ __launch_bounds__(256) void detect_mask_kernel(
    const unsigned int* __restrict__ m, int* __restrict__ flag)
{
    __shared__ unsigned int r123, r01, r23;
    if (threadIdx.x == 0) { r123 = 0; r01 = 0; r23 = 0; }
    __syncthreads();
    unsigned int a123 = 0, a01 = 0, a23 = 0;
    #pragma unroll
    for (int i = 0; i < 16; ++i) {
        unsigned int w = m[threadIdx.x * 16 + i];
        a123 |= (w & 0xFFFFFF00u);
        a01  |= (w & 0x0000FFFFu);
        a23  |= (w & 0xFFFF0000u);
    }
    if (a123) atomicOr(&r123, 1u);
    if (a01)  atomicOr(&r01, 1u);
    if (a23)  atomicOr(&r23, 1u);
    __syncthreads();
    if (threadIdx.x == 0) {
        int f;
        if (!r123)            f = 0;  // int32 {0,1}
        else if (!r01 && r23) f = 2;  // float32 {0,1.0f}
        else                  f = 1;  // uint8 bool
        *flag = f;
    }
}

// ---------------- canon: per-b bitmask words [4][2176][68], pad folded in ------------
__global__ __launch_bounds__(256) void canon_bits_kernel(
    const void* __restrict__ mraw, const int* __restrict__ flag,
    const int* __restrict__ lengths, unsigned int* __restrict__ bits)
{
    int idx = blockIdx.x * 256 + threadIdx.x;
    if (idx >= NBITW) return;
    int b = idx / (QLEN * 68);
    int rem = idx - b * (QLEN * 68);
    int q = rem / 68, w = rem - q * 68;
    int kv0 = w * 32;
    int f = *flag;
    unsigned int out = 0;
    if (f == 0) {
        const int* p = (const int*)mraw + (size_t)q * QLEN + kv0;
        #pragma unroll
        for (int j = 0; j < 32; ++j) out |= (p[j] != 0) ? (1u << j) : 0u;
    } else if (f == 2) {
        const float* p = (const float*)mraw + (size_t)q * QLEN + kv0;
        #pragma unroll
        for (int j = 0; j < 32; ++j) out |= (p[j] != 0.0f) ? (1u << j) : 0u;
    } else {
        const unsigned char* p = (const unsigned char*)mraw + (size_t)q * QLEN + kv0;
        #pragma unroll
        for (int j = 0; j < 32; ++j) out |= p[j] ? (1u << j) : 0u;
    }
    int n = (128 + lengths[b]) - kv0;   // pad: kv >= 128+lengths[b] -> masked
    unsigned int pm = (n <= 0) ? 0xFFFFFFFFu : (n >= 32 ? 0u : (0xFFFFFFFFu << n));
    bits[idx] = out | pm;
}

// ---------------- concat 3 segments (f32) -> bf16 [8704][512] ----------------
__global__ __launch_bounds__(256) void conv_concat(
    const float* __restrict__ s0, const float* __restrict__ s1, const float* __restrict__ s2,
    int b0, int b1, ushort_t* __restrict__ dst)
{
    int c = blockIdx.x * 256 + threadIdx.x;
    int row = c >> 6, ch = c & 63;
    if (row >= NROWS) return;
    const float* src;
    if (row < b0)      src = s0 + (size_t)row * 512;
    else if (row < b1) src = s1 + (size_t)(row - b0) * 512;
    else               src = s2 + (size_t)(row - b1) * 512;
    float4 v0 = *(const float4*)(src + ch * 8);
    float4 v1 = *(const float4*)(src + ch * 8 + 4);
    short8 o;
    o[0] = (short)f2bf(v0.x); o[1] = (short)f2bf(v0.y);
    o[2] = (short)f2bf(v0.z); o[3] = (short)f2bf(v0.w);
    o[4] = (short)f2bf(v1.x); o[5] = (short)f2bf(v1.y);
    o[6] = (short)f2bf(v1.z); o[7] = (short)f2bf(v1.w);
    *(short8*)(dst + (size_t)row * 512 + ch * 8) = o;
}

// ---------------- W [512][N] f32 -> Wt [N][512] bf16 ----------------
__global__ __launch_bounds__(256) void transpose_w(
    const float* __restrict__ W, ushort_t* __restrict__ Wt, int N)
{
    __shared__ float t[32][33];
    int n0 = blockIdx.x * 32, k0 = blockIdx.y * 32;
    int tx = threadIdx.x, ty = threadIdx.y;
    #pragma unroll
    for (int i = 0; i < 4; ++i)
        t[ty + 8 * i][tx] = W[(size_t)(k0 + ty + 8 * i) * N + n0 + tx];
    __syncthreads();
    #pragma unroll
    for (int i = 0; i < 4; ++i)
        Wt[(size_t)(n0 + ty + 8 * i) * 512 + k0 + tx] = f2bf(t[tx][ty + 8 * i]);
}

// ---------------- bf16 MFMA GEMM (verified r3): C = A @ Bt^T + bias ----------------
template<int MODE>
__global__ __launch_bounds__(256) void gemm_mfma(
    const ushort_t* __restrict__ A, const ushort_t* __restrict__ Bt,
    const float* __restrict__ bias, float scale,
    ushort_t* __restrict__ dst0, ushort_t* __restrict__ dst1,
    float* __restrict__ dstf)
{
    __shared__ __align__(16) ushort_t As[128][40];
    __shared__ __align__(16) ushort_t Bs[128][40];
    const int tid = threadIdx.x;
    const int wid = tid >> 6, lane = tid & 63, lr = lane & 15, lg = lane >> 4;
    const int wm = wid >> 1, wn = wid & 1;
    const int bm = blockIdx.x, bn = blockIdx.y;

    f32x4 acc[4][4] = {};

    for (int k0 = 0; k0 < 512; k0 += 32) {
        __syncthreads();
        #pragma unroll
        for (int p = 0; p < 2; ++p) {
            int c = p * 256 + tid;
            int row = c >> 2, ch = c & 3;
            *(short8*)&As[row][ch * 8] =
                *(const short8*)(A + (size_t)(bm * 128 + row) * 512 + k0 + ch * 8);
            *(short8*)&Bs[row][ch * 8] =
                *(const short8*)(Bt + (size_t)(bn * 128 + row) * 512 + k0 + ch * 8);
        }
        __syncthreads();
        short8 af[4], bf[4];
        #pragma unroll
        for (int i = 0; i < 4; ++i) {
            af[i] = *(const short8*)&As[wm * 64 + i * 16 + lr][lg * 8];
            bf[i] = *(const short8*)&Bs[wn * 64 + i * 16 + lr][lg * 8];
        }
        #pragma unroll
        for (int i = 0; i < 4; ++i)
            #pragma unroll
            for (int j = 0; j < 4; ++j)
                acc[i][j] = MFMA16(af[i], bf[j], acc[i][j]);
    }

    #pragma unroll
    for (int i = 0; i < 4; ++i) {
        #pragma unroll
        for (int j = 0; j < 4; ++j) {
            int gc = bn * 128 + wn * 64 + j * 16 + lr;
            float bv = bias[gc];
            #pragma unroll
            for (int r = 0; r < 4; ++r) {
                int gr = bm * 128 + wm * 64 + i * 16 + lg * 4 + r;
                float v = (acc[i][j][r] + bv) * scale;
                if (MODE == 0) {
                    int cc = gc;
                    ushort_t* d = dst0;
                    if (cc >= 512) { cc -= 512; d = dst1; }
                    int pos = gr >> 2, bb = gr & 3;
                    d[(((size_t)bb * 8 + (cc >> 6)) * QLEN + pos) * 64 + (cc & 63)] = f2bf(v);
                } else {
                    int q = gr >> 2, bb = gr & 3;
                    if (q < 2112) {
                        dstf[(size_t)gr * 512 + gc] = v;
                    } else if (q < 2175) {
                        float cv = fminf(10.0f, fmaxf(-10.0f, v));
                        dstf[(size_t)2112 * 4 * 512 + ((size_t)(q - 2112) * 4 + bb) * 512 + gc] = cv;
                    } // q == 2175 dropped
                }
            }
        }
    }
}

// ---------------- Flash attention, swapped-QK^T 32x32 MFMA, in-register softmax -------
// 544 blocks (17 q-tiles x 32 bh, XCD-swizzled), 4 waves x 32 q-rows, KV tile 64.
// S^T = mfma32(K, Q): lane owns q = q0w + (lane&31); kv rows split across lane^32.
// C layout (m74/m101): col = lane&31, row = (reg&3) + 8*(reg>>2) + 4*(lane>>5).
__global__ __launch_bounds__(256) void attn_mfma32(
    const ushort_t* __restrict__ Qa, const ushort_t* __restrict__ Ka,
    const ushort_t* __restrict__ Va,
    const unsigned int* __restrict__ mbits,   // [4][2176][68]
    ushort_t* __restrict__ attnb)             // [q*4+b][512] bf16
{
    __shared__ __align__(16) ushort_t Ks[64][72];   // [kv][dh]
    __shared__ __align__(16) ushort_t Vt[64][72];   // [dh][kv]

    // XCD-aware swizzle: 544 % 8 == 0 -> bijective
    const int swz = (blockIdx.x & 7) * 68 + (blockIdx.x >> 3);
    const int qt = swz % 17, bh = swz / 17;
    const int b = bh >> 3, h = bh & 7;
    const int tid = threadIdx.x;
    const int w = tid >> 6, lane = tid & 63;
    const int ql = lane & 31, hi = lane >> 5;
    const size_t hb = (size_t)bh * QLEN * 64;
    const int qrow = qt * 128 + w * 32 + ql;

    // Q B-frags (register-resident): bq[m][j] = Q[qrow][m*16 + hi*8 + j]
    short8 bq[4];
    #pragma unroll
    for (int m = 0; m < 4; ++m)
        bq[m] = *(const short8*)(Qa + hb + (size_t)qrow * 64 + m * 16 + hi * 8);

    const unsigned int* mrow = mbits + ((size_t)b * QLEN + qrow) * 68;

    f32x16 oacc[2] = {};            // O^T[d = 32*dt + rl][q]
    float mr = -INFINITY, lr = 0.0f;

    for (int kt = 0; kt < 34; ++kt) {
        const int k0 = kt * 64;
        __syncthreads();
        // stage K [kv][dh]
        #pragma unroll
        for (int p = 0; p < 2; ++p) {
            int c = p * 256 + tid;
            int row = c >> 3, ch = c & 7;
            *(short8*)&Ks[row][ch * 8] =
                *(const short8*)(Ka + hb + (size_t)(k0 + row) * 64 + ch * 8);
        }
        // stage V transposed [dh][kv]
        #pragma unroll
        for (int p = 0; p < 2; ++p) {
            int c = p * 256 + tid;
            int kv = c & 63, ch = c >> 6;
            short8 v = *(const short8*)(Va + hb + (size_t)(k0 + kv) * 64 + ch * 8);
            #pragma unroll
            for (int i = 0; i < 8; ++i) Vt[ch * 8 + i][kv] = (ushort_t)v[i];
        }
        __syncthreads();

        // S^T[kv][q]: st[t][reg] = S[kv = k0 + 32t + rl][qrow]
        f32x16 st[2] = {};
        #pragma unroll
        for (int t = 0; t < 2; ++t)
            #pragma unroll
            for (int m = 0; m < 4; ++m) {
                short8 ak = *(const short8*)&Ks[t * 32 + ql][m * 16 + hi * 8];
                st[t] = MFMA32(ak, bq[m], st[t]);
            }

        // mask + online softmax (q is lane-local; kv split only across lane^32)
        unsigned int wm0 = mrow[kt * 2]     >> (hi * 4);
        unsigned int wm1 = mrow[kt * 2 + 1] >> (hi * 4);
        float p[2][16];
        float pmax = -INFINITY;
        #pragma unroll
        for (int t = 0; t < 2; ++t) {
            unsigned int wt = t ? wm1 : wm0;
            #pragma unroll
            for (int r = 0; r < 16; ++r) {
                const int rl = (r & 3) + 8 * (r >> 2);
                float x = st[t][r];
                x = ((wt >> rl) & 1u) ? NEG_INF_V : x;
                p[t][r] = x;
                pmax = fmaxf(pmax, x);
            }
        }
        pmax = fmaxf(pmax, __shfl_xor(pmax, 32));
        float mn = fmaxf(mr, pmax);
        float fac = __expf(mr - mn);
        float rs = 0.0f;
        #pragma unroll
        for (int t = 0; t < 2; ++t)
            #pragma unroll
            for (int r = 0; r < 16; ++r) {
                float e = __expf(p[t][r] - mn);
                p[t][r] = e;
                rs += e;
            }
        rs += __shfl_xor(rs, 32);
        lr = lr * fac + rs;
        mr = mn;
        #pragma unroll
        for (int dt = 0; dt < 2; ++dt)
            #pragma unroll
            for (int r = 0; r < 16; ++r) oacc[dt][r] *= fac;

        // P^T -> bf16 B-frags in-register: 16 cvt_pk + 8 permlane32_swap.
        // b-frag c needs octet o = 2c+hi: VGPRs = {P0,P1,P2,P3}(o).
        unsigned int bw[4][4];
        #pragma unroll
        for (int c = 0; c < 4; ++c) {
            const int t0 = c >> 1, s0 = (2 * c) & 3, s1 = s0 + 1;
            unsigned int A = cvtpk_bf16(p[t0][4 * s0 + 0], p[t0][4 * s0 + 1]);
            unsigned int B = cvtpk_bf16(p[t0][4 * s1 + 0], p[t0][4 * s1 + 1]);
            unsigned int C = cvtpk_bf16(p[t0][4 * s0 + 2], p[t0][4 * s0 + 3]);
            unsigned int D = cvtpk_bf16(p[t0][4 * s1 + 2], p[t0][4 * s1 + 3]);
            asm volatile("v_permlane32_swap_b32 %0, %1" : "+v"(A), "+v"(B));
            asm volatile("v_permlane32_swap_b32 %0, %1" : "+v"(C), "+v"(D));
            bw[c][0] = A; bw[c][1] = C; bw[c][2] = B; bw[c][3] = D;
        }

        // O^T += V^T P^T : A-frag av[j] = V[kv = 16c + 8hi + j][d = 32dt + ql]
        #pragma unroll
        for (int c = 0; c < 4; ++c) {
            short8 bp;
            #pragma unroll
            for (int u = 0; u < 4; ++u) {
                bp[2 * u]     = (short)(bw[c][u] & 0xFFFFu);
                bp[2 * u + 1] = (short)(bw[c][u] >> 16);
            }
            #pragma unroll
            for (int dt = 0; dt < 2; ++dt) {
                short8 av = *(const short8*)&Vt[dt * 32 + ql][c * 16 + hi * 8];
                oacc[dt] = MFMA32(av, bp, oacc[dt]);
            }
        }
    }

    // normalize + write: lane holds d = 32dt + 8s + 4hi + u for its q
    float inv = 1.0f / lr;
    #pragma unroll
    for (int dt = 0; dt < 2; ++dt)
        #pragma unroll
        for (int s = 0; s < 4; ++s) {
            unsigned int lo = (unsigned int)f2bf(oacc[dt][4 * s + 0] * inv)
                            | ((unsigned int)f2bf(oacc[dt][4 * s + 1] * inv) << 16);
            unsigned int hi2 = (unsigned int)f2bf(oacc[dt][4 * s + 2] * inv)
                             | ((unsigned int)f2bf(oacc[dt][4 * s + 3] * inv) << 16);
            uint2 pk; pk.x = lo; pk.y = hi2;
            *(uint2*)(attnb + ((size_t)qrow * 4 + b) * 512 + h * 64 + dt * 32 + 8 * s + 4 * hi) = pk;
        }
}

extern "C" void kernel_launch(void* const* d_in, const int* in_sizes, int n_in,
                              void* d_out, int out_size, void* d_ws, size_t ws_size,
                              hipStream_t stream) {
    const float* utterance     = (const float*)d_in[0];
    const int*   lengths       = (const int*)d_in[1];
    const float* right_context = (const float*)d_in[2];
    const float* summary       = (const float*)d_in[3];
    const float* memory        = (const float*)d_in[4];
    const void*  mask_raw      = d_in[5];
    const float* w_q   = (const float*)d_in[6];
    const float* b_q   = (const float*)d_in[7];
    const float* w_kv  = (const float*)d_in[8];
    const float* b_kv  = (const float*)d_in[9];
    const float* w_out = (const float*)d_in[10];
    const float* b_out = (const float*)d_in[11];
    float* out = (float*)d_out;

    char* ws = (char*)d_ws;
    const size_t SZ = (size_t)NROWS * 512 * 2;             // 8.9 MB per bf16 matrix
    ushort_t* qin    = (ushort_t*)(ws);                    // [8704][512]
    ushort_t* kvin   = (ushort_t*)(ws + SZ);
    ushort_t* q_attn = (ushort_t*)(ws + 2 * SZ);           // [bh][2176][64]
    ushort_t* k_attn = (ushort_t*)(ws + 3 * SZ);
    ushort_t* v_attn = (ushort_t*)(ws + 4 * SZ);
    ushort_t* attnb  = (ushort_t*)(ws + 5 * SZ);
    ushort_t* wtq    = (ushort_t*)(ws + 6 * SZ);           // [512][512]
    ushort_t* wtkv   = wtq + (size_t)512 * 512;            // [1024][512]
    ushort_t* wtout  = wtkv + (size_t)1024 * 512;          // [512][512]
    unsigned int* mbits = (unsigned int*)(wtout + (size_t)512 * 512);  // [4][2176][68]
    int* maskflag = (int*)(mbits + NBITW);

    // mask dtype detect + bitmask canon (pad folded per-b)
    detect_mask_kernel<<<1, 256, 0, stream>>>((const unsigned int*)mask_raw, maskflag);
    canon_bits_kernel<<<(NBITW + 255) / 256, 256, 0, stream>>>(mask_raw, maskflag, lengths, mbits);

    // activations -> bf16
    conv_concat<<<2176, 256, 0, stream>>>(right_context, utterance, summary, 256, 8448, qin);
    conv_concat<<<2176, 256, 0, stream>>>(memory, right_context, utterance, 256, 512, kvin);

    // weights -> transposed bf16 [N][512]
    transpose_w<<<dim3(16, 16), dim3(32, 8), 0, stream>>>(w_q, wtq, 512);
    transpose_w<<<dim3(32, 16), dim3(32, 8), 0, stream>>>(w_kv, wtkv, 1024);
    transpose_w<<<dim3(16, 16), dim3(32, 8), 0, stream>>>(w_out, wtout, 512);

    // projections (Q pre-scaled by dh^-0.5 = 0.125)
    gemm_mfma<0><<<dim3(68, 4), 256, 0, stream>>>(qin, wtq, b_q, 0.125f, q_attn, q_attn, nullptr);
    gemm_mfma<0><<<dim3(68, 8), 256, 0, stream>>>(kvin, wtkv, b_kv, 1.0f, k_attn, v_attn, nullptr);

    // attention (544 blocks, XCD-swizzled in-kernel)
    attn_mfma32<<<544, 256, 0, stream>>>(q_attn, k_attn, v_attn, mbits, attnb);

    // output projection + routing epilogue
    gemm_mfma<1><<<dim3(68, 4), 256, 0, stream>>>(attnb, wtout, b_out, 1.0f, nullptr, nullptr, out);
}